// Round 13
// baseline (2513.893 us; speedup 1.0000x reference)
//
#include <hip/hip_runtime.h>

#define BS    32
#define MDIM  256
#define NDIM  512
#define ITERS 1000
#define BLK   512
#define NWG   128
#define ALPHA 0.02f
#define BETA  0.02f

// R13 = R11 + two-tier poll. Producers dual-publish w: plain store (lands in
// the shared per-XCD L2 if the batch's 4 wgs are co-resident — mapping
// evidence: R4/R12 locality regressions) + agent-scope store (LLC, proven).
// Consumers: cheap sc0 HINT sample (local L2, ~150-250cy period, no LLC
// traffic) gates the proven agent-scope fetch; CONSUMED DATA ALWAYS comes
// from the agent-scope load + tag validation (byte-identical trust to R11).
// Stale/tag-wrapped hints (R7's deadlock class; 256-iter wrap false-match)
// can only trigger an early authoritative fetch-spin -> blocks till the true
// tag arrives. Liveness: every poll round contains the proven agent sample.
// Removes the detect-quantization term (~300-600cy/iter) without touching
// LLC sample rate (R9's mistake: fast-sampling the LLC itself).

// ---- LDS (floats) ----
#define ATS      520                 // prologue A-tile [32][520] + b[32]
#define BT_OFF   (32 * ATS)          // 16640
#define C_OFF    (BT_OFF + 32)       // c slice [128]
#define P_OFF    0                   // iteration partials [128][12] reuse A-tile
#define PSTRIDE  12                  // 48B rows: float4-aligned
#define SMEM_FL  21504               // 86016 B -> 1 wg/CU (baseline-proven)

// Exchange slab: [2 parity][BS][512] floats, mantissa-tagged (low 8 bits =
// (k+1)&255): every word self-validates. Tag-gating bounds drift <2 iters;
// owners in every wave => a wave stores k+1 only after its owners finished
// iter-k partial reads => poll k+1 passing implies all 32 waves done with k.
#define SLAB_FL  (2 * BS * NDIM)

__device__ __forceinline__ unsigned ld_coh_u32(const void* p) {
  return __hip_atomic_load(reinterpret_cast<const unsigned*>(p),
                           __ATOMIC_RELAXED, __HIP_MEMORY_SCOPE_AGENT);
}
__device__ __forceinline__ void st_coh_u32(void* p, unsigned v) {
  __hip_atomic_store(reinterpret_cast<unsigned*>(p), v,
                     __ATOMIC_RELAXED, __HIP_MEMORY_SCOPE_AGENT);
}
// L2-domain flavors (hint path only; sc0 = L1-bypass, L2-served; spelling
// proven to assemble+run on gfx950 by R9's bench).
__device__ __forceinline__ unsigned ld_l2_u32(const void* p) {
  unsigned v;
  asm volatile("global_load_dword %0, %1, off sc0\n\t"
               "s_waitcnt vmcnt(0)"
               : "=v"(v) : "v"(p) : "memory");
  return v;
}
__device__ __forceinline__ void st_l2_u32(void* p, unsigned v) {
  asm volatile("global_store_dword %0, %1, off"
               :: "v"(p), "v"(v) : "memory");
}
__device__ __forceinline__ unsigned tagf(float v, unsigned tag) {
  return (__float_as_uint(v) & ~0xFFu) | tag;
}

__global__ __launch_bounds__(BLK, 1) void pdhg_kernel(
    const float* __restrict__ A, const float* __restrict__ Bvec,
    float* __restrict__ out, float* __restrict__ slab)
{
  __shared__ float smem[SMEM_FL];
  const int tid   = threadIdx.x;
  const int bid   = blockIdx.x;
  const int batch = bid & (BS - 1);    // XCD-local mapping (proven best)
  const int slice = bid >> 5;          // wg owns G-rows [128*slice, +128)
  const int lane  = tid & 63;
  const int widx  = tid >> 6;          // wave's cols = [64*widx, +64)
  const int rg    = lane >> 3;         // row group: rows [16*rg, +16) (local)
  const int cg    = lane & 7;          // col group: cols 64*widx + 8*cg + [0,8)

  const int ibase = 128 * slice + 16 * rg;   // global row base of acc
  const int jbase = 64 * widx + 8 * cg;      // global col base of acc

  // ================= PROLOGUE: G tile in regs, c = A^T b ===================
  float acc[16][8];                    // acc[r][c] = G[ibase+r][jbase+c]
#pragma unroll
  for (int r = 0; r < 16; ++r)
#pragma unroll
    for (int c = 0; c < 8; ++c) acc[r][c] = 0.f;
  float cacc = 0.f;                    // tid<128: c[128*slice + tid]

  const float* Ag = A + (size_t)batch * MDIM * NDIM;

  for (int mt = 0; mt < MDIM / 32; ++mt) {
    // stage A[mt*32..+32, :] as [32][ATS] (baseline-verbatim, coalesced)
#pragma unroll 4
    for (int q = 0; q < 8; ++q) {
      int f  = q * 512 + tid;          // float4 index in 32x512 tile
      int mm = f >> 7;
      int j  = (f & 127) << 2;
      float4 v = *reinterpret_cast<const float4*>(
          Ag + (size_t)(mt * 32 + mm) * NDIM + j);
      *reinterpret_cast<float4*>(&smem[mm * ATS + j]) = v;
    }
    if (tid < 32) smem[BT_OFF + tid] = Bvec[batch * MDIM + mt * 32 + tid];
    __syncthreads();

#pragma unroll 2
    for (int m = 0; m < 32; ++m) {
      const float* row = &smem[m * ATS];
      // ai[16]: 4x float4, 8-way broadcast over cg -> free
      float4 a0 = *reinterpret_cast<const float4*>(row + ibase);
      float4 a1 = *reinterpret_cast<const float4*>(row + ibase + 4);
      float4 a2 = *reinterpret_cast<const float4*>(row + ibase + 8);
      float4 a3 = *reinterpret_cast<const float4*>(row + ibase + 12);
      float ai[16] = {a0.x,a0.y,a0.z,a0.w, a1.x,a1.y,a1.z,a1.w,
                      a2.x,a2.y,a2.z,a2.w, a3.x,a3.y,a3.z,a3.w};
      // aj[8]: 2x float4, 8-way broadcast over rg
      float4 j0 = *reinterpret_cast<const float4*>(row + jbase);
      float4 j1 = *reinterpret_cast<const float4*>(row + jbase + 4);
      float aj[8] = {j0.x,j0.y,j0.z,j0.w, j1.x,j1.y,j1.z,j1.w};
      float bm = smem[BT_OFF + m];
#pragma unroll
      for (int r = 0; r < 16; ++r)
#pragma unroll
        for (int c = 0; c < 8; ++c) acc[r][c] = fmaf(ai[r], aj[c], acc[r][c]);
      if (tid < 128) cacc = fmaf(row[128 * slice + tid], bm, cacc);
    }
    __syncthreads();
  }
  if (tid < 128) smem[C_OFF + tid] = cacc;
  __syncthreads();

  // ================= ITERATION ============================================
  const bool owner = (tid & 3) == 0;
  const int  Rloc  = tid >> 2;                 // owner's local row 0..127
  const float c_reg = owner ? smem[C_OFF + Rloc] : 0.f;
  float x = 0.f, t = 0.f;

  float*       myslot = slab + batch * NDIM + 128 * slice + Rloc;  // +parity
  const float* myrd   = slab + batch * NDIM + tid;   // coalesced poll: word tid

  const int swzcol = widx ^ rg;        // bank-free partials column (R11)

  for (int k = 0; k < ITERS; ++k) {
    float xn = 0.f;
    if (owner) {
      float y = x - ALPHA * t;
      xn = fmaxf(y - ALPHA, 0.f) - fmaxf(-y - ALPHA, 0.f);
    }
    if (k == ITERS - 1) { x = xn; break; }

    const int      par = (k & 1) * BS * NDIM;
    const unsigned tag = (unsigned)(k + 1) & 0xFFu;
    if (owner) {
      float wv_ = 2.f * xn - x;
      x = xn;
      unsigned pv = tagf(wv_, tag);
      st_l2_u32(myslot + par, pv);     // fast-domain publish (shared L2)
      st_coh_u32(myslot + par, pv);    // authoritative publish (LLC, proven)
    }

    // two-tier poll: sc0 hint (cheap, local-L2) gates the authoritative
    // agent-scope fetch. Consumed value ALWAYS from the agent load + tag
    // check (= R11 trust). Every round contains an agent sample (liveness).
    unsigned q;
    for (;;) {
      unsigned h = ld_l2_u32(myrd + par);          // hint sample
      if (((h ^ tag) & 0xFFu) == 0u) {
        do { q = ld_coh_u32(myrd + par); } while ((q ^ tag) & 0xFFu);
        break;                                     // fresh-validated
      }
      q = ld_coh_u32(myrd + par);                  // progress sample
      if (((q ^ tag) & 0xFFu) == 0u) break;
    }
    float w_own = __uint_as_float(q);

    // w gather: lane's 8 cols live in lanes 8*cg..8*cg+7 of THIS wave
    float wv[8];
#pragma unroll
    for (int c = 0; c < 8; ++c) wv[c] = __shfl(w_own, 8 * cg + c);

    float S[16];
#pragma unroll
    for (int r = 0; r < 16; ++r) {
      float p = acc[r][0] * wv[0];
#pragma unroll
      for (int c = 1; c < 8; ++c) p = fmaf(acc[r][c], wv[c], p);
      S[r] = p;
    }

    // 3-stage value-halving butterfly over cg bits (R3-verified pattern,
    // stages 1,2,4): V[i] = full-wave sum for local row 16*rg + 8*i + cg.
    const bool b0 = (lane & 1), b1 = (lane & 2), b2 = (lane & 4);
    float T[8];
#pragma unroll
    for (int i = 0; i < 8; ++i) {
      float keep = b0 ? S[2*i+1] : S[2*i];
      float send = b0 ? S[2*i]   : S[2*i+1];
      T[i] = keep + __shfl_xor(send, 1);
    }
    float U[4];
#pragma unroll
    for (int i = 0; i < 4; ++i) {
      float keep = b1 ? T[2*i+1] : T[2*i];
      float send = b1 ? T[2*i]   : T[2*i+1];
      U[i] = keep + __shfl_xor(send, 2);
    }
    float V[2];
#pragma unroll
    for (int i = 0; i < 2; ++i) {
      float keep = b2 ? U[2*i+1] : U[2*i];
      float send = b2 ? U[2*i]   : U[2*i+1];
      V[i] = keep + __shfl_xor(send, 4);
    }

    // wave-partials -> LDS [128][12] at swizzled column widx^rg (R11):
    // exactly 2 lanes/bank = free; per-row bijection invisible to the owner.
    smem[P_OFF + (16 * rg + cg)     * PSTRIDE + swzcol] = V[0];
    smem[P_OFF + (16 * rg + 8 + cg) * PSTRIDE + swzcol] = V[1];
    __syncthreads();

    if (owner) {
      const float* pp = &smem[P_OFF + Rloc * PSTRIDE];   // 2-way banks: free
      float4 pa = *reinterpret_cast<const float4*>(pp);
      float4 pb = *reinterpret_cast<const float4*>(pp + 4);
      float s8 = (pa.x + pa.y) + (pa.z + pa.w) +
                 (pb.x + pb.y) + (pb.z + pb.w);
      t += BETA * (s8 - c_reg);          // t_{k+1} = t_k + beta*(Gw - c)
    }
  }

  // ---- epilogue: owners write x slice ----
  if (owner) out[(size_t)batch * NDIM + 128 * slice + Rloc] = x;
}

extern "C" void kernel_launch(void* const* d_in, const int* in_sizes, int n_in,
                              void* d_out, int out_size, void* d_ws, size_t ws_size,
                              hipStream_t stream) {
  const float* A = (const float*)d_in[0];
  const float* b = (const float*)d_in[1];
  float* out  = (float*)d_out;
  float* slab = (float*)d_ws;                    // 128 KiB w-exchange slab

  hipMemsetAsync(d_ws, 0, SLAB_FL * sizeof(float), stream);  // tag 0 != 1,2

  void* args[] = {(void*)&A, (void*)&b, (void*)&out, (void*)&slab};
  hipLaunchCooperativeKernel((const void*)pdhg_kernel, dim3(NWG), dim3(BLK),
                             args, 0, stream);
}

// Round 14
// 1486.968 us; speedup vs baseline: 1.6906x; 1.6906x over previous
//
#include <hip/hip_runtime.h>

#define BS    32
#define MDIM  256
#define NDIM  512
#define ITERS 1000
#define BLK   512
#define NWG   128
#define ALPHA 0.02f
#define BETA  0.02f

// R14 = R11 verbatim (final): best verified kernel of the session, 1508us.
// R13's two-tier poll doubled WRITE_SIZE (dual publish) and regressed ->
// pre-committed conclusion: the agent-scope exchange (~2800cy/iter:
// store-visibility + detect at the LLC coherence point) is this problem's
// structural floor; every attempt to cheat it (flood/pipelined/sc0sc1/hint
// polls, flags, cross-batch pipelining, L2-local exchange) regressed or
// deadlocked. R11's structure: stage-free iteration (wave's G-cols == its
// own polled words -> 8 __shfl gather), 3-stage halving butterfly, XOR-
// swizzled partials (2 lanes/bank = free), ONE barrier, owners update t/x.

// ---- LDS (floats) ----
#define ATS      520                 // prologue A-tile [32][520] + b[32]
#define BT_OFF   (32 * ATS)          // 16640
#define C_OFF    (BT_OFF + 32)       // c slice [128]
#define P_OFF    0                   // iteration partials [128][12] reuse A-tile
#define PSTRIDE  12                  // 48B rows: float4-aligned
#define SMEM_FL  21504               // 86016 B -> 1 wg/CU (baseline-proven)

// Exchange slab: [2 parity][BS][512] floats, mantissa-tagged (low 8 bits =
// (k+1)&255): every word self-validates. Tag-gating bounds drift <2 iters;
// owners in every wave => a wave stores k+1 only after its owners finished
// iter-k partial reads => poll k+1 passing implies all 32 waves done with k.
#define SLAB_FL  (2 * BS * NDIM)

__device__ __forceinline__ unsigned ld_coh_u32(const void* p) {
  return __hip_atomic_load(reinterpret_cast<const unsigned*>(p),
                           __ATOMIC_RELAXED, __HIP_MEMORY_SCOPE_AGENT);
}
__device__ __forceinline__ void st_coh_u32(void* p, unsigned v) {
  __hip_atomic_store(reinterpret_cast<unsigned*>(p), v,
                     __ATOMIC_RELAXED, __HIP_MEMORY_SCOPE_AGENT);
}
__device__ __forceinline__ unsigned tagf(float v, unsigned tag) {
  return (__float_as_uint(v) & ~0xFFu) | tag;
}

__global__ __launch_bounds__(BLK, 1) void pdhg_kernel(
    const float* __restrict__ A, const float* __restrict__ Bvec,
    float* __restrict__ out, float* __restrict__ slab)
{
  __shared__ float smem[SMEM_FL];
  const int tid   = threadIdx.x;
  const int bid   = blockIdx.x;
  const int batch = bid & (BS - 1);    // XCD-local mapping (proven best)
  const int slice = bid >> 5;          // wg owns G-rows [128*slice, +128)
  const int lane  = tid & 63;
  const int widx  = tid >> 6;          // wave's cols = [64*widx, +64)
  const int rg    = lane >> 3;         // row group: rows [16*rg, +16) (local)
  const int cg    = lane & 7;          // col group: cols 64*widx + 8*cg + [0,8)

  const int ibase = 128 * slice + 16 * rg;   // global row base of acc
  const int jbase = 64 * widx + 8 * cg;      // global col base of acc

  // ================= PROLOGUE: G tile in regs, c = A^T b ===================
  float acc[16][8];                    // acc[r][c] = G[ibase+r][jbase+c]
#pragma unroll
  for (int r = 0; r < 16; ++r)
#pragma unroll
    for (int c = 0; c < 8; ++c) acc[r][c] = 0.f;
  float cacc = 0.f;                    // tid<128: c[128*slice + tid]

  const float* Ag = A + (size_t)batch * MDIM * NDIM;

  for (int mt = 0; mt < MDIM / 32; ++mt) {
    // stage A[mt*32..+32, :] as [32][ATS] (baseline-verbatim, coalesced)
#pragma unroll 4
    for (int q = 0; q < 8; ++q) {
      int f  = q * 512 + tid;          // float4 index in 32x512 tile
      int mm = f >> 7;
      int j  = (f & 127) << 2;
      float4 v = *reinterpret_cast<const float4*>(
          Ag + (size_t)(mt * 32 + mm) * NDIM + j);
      *reinterpret_cast<float4*>(&smem[mm * ATS + j]) = v;
    }
    if (tid < 32) smem[BT_OFF + tid] = Bvec[batch * MDIM + mt * 32 + tid];
    __syncthreads();

#pragma unroll 2
    for (int m = 0; m < 32; ++m) {
      const float* row = &smem[m * ATS];
      // ai[16]: 4x float4, 8-way broadcast over cg -> free
      float4 a0 = *reinterpret_cast<const float4*>(row + ibase);
      float4 a1 = *reinterpret_cast<const float4*>(row + ibase + 4);
      float4 a2 = *reinterpret_cast<const float4*>(row + ibase + 8);
      float4 a3 = *reinterpret_cast<const float4*>(row + ibase + 12);
      float ai[16] = {a0.x,a0.y,a0.z,a0.w, a1.x,a1.y,a1.z,a1.w,
                      a2.x,a2.y,a2.z,a2.w, a3.x,a3.y,a3.z,a3.w};
      // aj[8]: 2x float4, 8-way broadcast over rg
      float4 j0 = *reinterpret_cast<const float4*>(row + jbase);
      float4 j1 = *reinterpret_cast<const float4*>(row + jbase + 4);
      float aj[8] = {j0.x,j0.y,j0.z,j0.w, j1.x,j1.y,j1.z,j1.w};
      float bm = smem[BT_OFF + m];
#pragma unroll
      for (int r = 0; r < 16; ++r)
#pragma unroll
        for (int c = 0; c < 8; ++c) acc[r][c] = fmaf(ai[r], aj[c], acc[r][c]);
      if (tid < 128) cacc = fmaf(row[128 * slice + tid], bm, cacc);
    }
    __syncthreads();
  }
  if (tid < 128) smem[C_OFF + tid] = cacc;
  __syncthreads();

  // ================= ITERATION ============================================
  const bool owner = (tid & 3) == 0;
  const int  Rloc  = tid >> 2;                 // owner's local row 0..127
  const float c_reg = owner ? smem[C_OFF + Rloc] : 0.f;
  float x = 0.f, t = 0.f;

  float*       myslot = slab + batch * NDIM + 128 * slice + Rloc;  // +parity
  const float* myrd   = slab + batch * NDIM + tid;   // coalesced poll: word tid

  const int swzcol = widx ^ rg;        // bank-free partials column (R11)

  for (int k = 0; k < ITERS; ++k) {
    float xn = 0.f;
    if (owner) {
      float y = x - ALPHA * t;
      xn = fmaxf(y - ALPHA, 0.f) - fmaxf(-y - ALPHA, 0.f);
    }
    if (k == ITERS - 1) { x = xn; break; }

    const int      par = (k & 1) * BS * NDIM;
    const unsigned tag = (unsigned)(k + 1) & 0xFFu;
    if (owner) {
      float wv_ = 2.f * xn - x;
      x = xn;
      st_coh_u32(myslot + par, tagf(wv_, tag));
    }

    // poll own word (self-validating mantissa tag; proven dependent spin)
    unsigned q;
    do { q = ld_coh_u32(myrd + par); } while ((q ^ tag) & 0xFFu);
    float w_own = __uint_as_float(q);

    // w gather: lane's 8 cols live in lanes 8*cg..8*cg+7 of THIS wave
    float wv[8];
#pragma unroll
    for (int c = 0; c < 8; ++c) wv[c] = __shfl(w_own, 8 * cg + c);

    float S[16];
#pragma unroll
    for (int r = 0; r < 16; ++r) {
      float p = acc[r][0] * wv[0];
#pragma unroll
      for (int c = 1; c < 8; ++c) p = fmaf(acc[r][c], wv[c], p);
      S[r] = p;
    }

    // 3-stage value-halving butterfly over cg bits (R3-verified pattern,
    // stages 1,2,4): V[i] = full-wave sum for local row 16*rg + 8*i + cg.
    const bool b0 = (lane & 1), b1 = (lane & 2), b2 = (lane & 4);
    float T[8];
#pragma unroll
    for (int i = 0; i < 8; ++i) {
      float keep = b0 ? S[2*i+1] : S[2*i];
      float send = b0 ? S[2*i]   : S[2*i+1];
      T[i] = keep + __shfl_xor(send, 1);
    }
    float U[4];
#pragma unroll
    for (int i = 0; i < 4; ++i) {
      float keep = b1 ? T[2*i+1] : T[2*i];
      float send = b1 ? T[2*i]   : T[2*i+1];
      U[i] = keep + __shfl_xor(send, 2);
    }
    float V[2];
#pragma unroll
    for (int i = 0; i < 2; ++i) {
      float keep = b2 ? U[2*i+1] : U[2*i];
      float send = b2 ? U[2*i]   : U[2*i+1];
      V[i] = keep + __shfl_xor(send, 4);
    }

    // wave-partials -> LDS [128][12] at swizzled column widx^rg: bank =
    // (12cg + widx^rg) mod 32 -> exactly 2 lanes/bank (free). Owner sums
    // all 8 columns of its row; the per-row bijection is invisible to it.
    smem[P_OFF + (16 * rg + cg)     * PSTRIDE + swzcol] = V[0];
    smem[P_OFF + (16 * rg + 8 + cg) * PSTRIDE + swzcol] = V[1];
    __syncthreads();

    if (owner) {
      const float* pp = &smem[P_OFF + Rloc * PSTRIDE];   // 2-way banks: free
      float4 pa = *reinterpret_cast<const float4*>(pp);
      float4 pb = *reinterpret_cast<const float4*>(pp + 4);
      float s8 = (pa.x + pa.y) + (pa.z + pa.w) +
                 (pb.x + pb.y) + (pb.z + pb.w);
      t += BETA * (s8 - c_reg);          // t_{k+1} = t_k + beta*(Gw - c)
    }
  }

  // ---- epilogue: owners write x slice ----
  if (owner) out[(size_t)batch * NDIM + 128 * slice + Rloc] = x;
}

extern "C" void kernel_launch(void* const* d_in, const int* in_sizes, int n_in,
                              void* d_out, int out_size, void* d_ws, size_t ws_size,
                              hipStream_t stream) {
  const float* A = (const float*)d_in[0];
  const float* b = (const float*)d_in[1];
  float* out  = (float*)d_out;
  float* slab = (float*)d_ws;                    // 128 KiB w-exchange slab

  hipMemsetAsync(d_ws, 0, SLAB_FL * sizeof(float), stream);  // tag 0 != 1,2

  void* args[] = {(void*)&A, (void*)&b, (void*)&out, (void*)&slab};
  hipLaunchCooperativeKernel((const void*)pdhg_kernel, dim3(NWG), dim3(BLK),
                             args, 0, stream);
}